// Round 10
// baseline (523.599 us; speedup 1.0000x reference)
//
#include <hip/hip_runtime.h>

#define N_NODES 100000
#define N_EDGES 3200000
#define N_FEAT 24
#define BSHIFT 7                        // 128 rows per bucket
#define BROWS 128
#define NBUCK ((N_NODES + BROWS - 1) >> BSHIFT)   // 782
#define EPT 16                          // edges per thread in partition
#define TILE (256 * EPT)                // 4096 edges per block-tile
#define NTILES ((N_EDGES + TILE - 1) / TILE)      // 782
#define CAP 4608                        // place stage entries (36KB) ~ mean+8sd
#define DMAX 256                        // degree buckets for balance sort
#define NKEY (BROWS * 16)               // 2048: (row_local 7b) x (colbin 4b)

// ---------------- small utils ----------------

__global__ void zero_kernel(int* __restrict__ p, int n) {
    int i = blockIdx.x * blockDim.x + threadIdx.x;
    if (i < n) p[i] = 0;
}

// ---------------- bucket histogram (LDS-aggregated) ----------------
__global__ __launch_bounds__(256) void bhist_kernel(const int* __restrict__ row,
                                                    int* __restrict__ bcnt) {
    __shared__ int h[NBUCK];
    for (int i = threadIdx.x; i < NBUCK; i += 256) h[i] = 0;
    __syncthreads();
    int stride = gridDim.x * blockDim.x;
    for (int i = blockIdx.x * blockDim.x + threadIdx.x; i < N_EDGES; i += stride)
        atomicAdd(&h[row[i] >> BSHIFT], 1);
    __syncthreads();
    for (int i = threadIdx.x; i < NBUCK; i += 256) {
        int c = h[i];
        if (c) atomicAdd(&bcnt[i], c);
    }
}

// ---------------- bucket exclusive scan -> bbase[0..NBUCK], bcursor ----------------
__global__ __launch_bounds__(1024) void bscan_kernel(const int* __restrict__ bcnt,
                                                     int* __restrict__ bbase,
                                                     int* __restrict__ bcursor) {
    __shared__ int part[1024];
    int tid = threadIdx.x;
    int v = (tid < NBUCK) ? bcnt[tid] : 0;
    part[tid] = v;
    __syncthreads();
    for (int off = 1; off < 1024; off <<= 1) {
        int p = (tid >= off) ? part[tid - off] : 0;
        __syncthreads();
        part[tid] += p;
        __syncthreads();
    }
    int ex = (tid > 0) ? part[tid - 1] : 0;
    if (tid <= NBUCK) {
        bbase[tid] = ex;              // bbase[NBUCK] == N_EDGES
        if (tid < NBUCK) bcursor[tid] = ex;
    }
}

// ---------------- level 1: partition edges into bucket regions ----------------
__global__ __launch_bounds__(256) void part_kernel(const int* __restrict__ row,
                                                   const int* __restrict__ col,
                                                   const float* __restrict__ val,
                                                   int* __restrict__ bcursor,
                                                   int2* __restrict__ epk) {
    __shared__ int h[NBUCK];
    __shared__ int lstart[NBUCK];
    __shared__ int delta[NBUCK];      // gpos[b] - lstart[b]
    __shared__ int psum[256];
    __shared__ int2 stage[TILE];
    __shared__ unsigned short bidx[TILE];
    const int tid = threadIdx.x;
    for (int i = tid; i < NBUCK; i += 256) h[i] = 0;
    __syncthreads();

    const int tbase = blockIdx.x * TILE;
    const int m = min(TILE, N_EDGES - tbase);
    const int base = tbase + tid * EPT;
    int rowj[EPT], rk[EPT];
    #pragma unroll
    for (int j = 0; j < EPT; ++j) {
        int e = base + j;
        if (e < N_EDGES) {
            int r = row[e];
            rowj[j] = r;
            rk[j] = atomicAdd(&h[r >> BSHIFT], 1);
        } else rowj[j] = -1;
    }
    __syncthreads();

    {   // exclusive scan h -> lstart (chunk=4 per thread, 256*4 >= NBUCK)
        int lo = tid * 4;
        int hi = min(NBUCK, lo + 4);
        int s = 0;
        for (int j = lo; j < hi; ++j) s += h[j];
        psum[tid] = s;
        __syncthreads();
        for (int off = 1; off < 256; off <<= 1) {
            int p = (tid >= off) ? psum[tid - off] : 0;
            __syncthreads();
            psum[tid] += p;
            __syncthreads();
        }
        int run = (tid > 0) ? psum[tid - 1] : 0;
        for (int j = lo; j < hi; ++j) {
            lstart[j] = run;
            run += h[j];
        }
    }
    __syncthreads();

    // reserve global chunks (one atomic per (block,bucket))
    for (int i = tid; i < NBUCK; i += 256) {
        int c = h[i];
        int g = c ? atomicAdd(&bcursor[i], c) : 0;
        delta[i] = g - lstart[i];
    }
    __syncthreads();

    #pragma unroll
    for (int j = 0; j < EPT; ++j) {
        if (rowj[j] >= 0) {
            int e = base + j;
            int b = rowj[j] >> BSHIFT;
            int rl = rowj[j] & (BROWS - 1);
            int slot = lstart[b] + rk[j];
            int2 pk;
            pk.x = col[e] | (rl << 17);   // col < 2^17, rl < 2^7
            pk.y = __float_as_int(val[e]);
            stage[slot] = pk;
            bidx[slot] = (unsigned short)b;
        }
    }
    __syncthreads();

    for (int i = tid; i < m; i += 256) {
        int b = bidx[i];
        epk[delta[b] + i] = stage[i];
    }
}

// ---------------- level 2: CSR placement, column-sorted within each row ----------------
// key = (row_local << 4) | (col >> 13). Emits starts[] + degree histogram.
__global__ __launch_bounds__(256) void place_kernel(const int* __restrict__ bbase,
                                                    int2* __restrict__ epk,
                                                    int* __restrict__ starts,
                                                    int* __restrict__ dcnt) {
    __shared__ int kcnt[NKEY];       // 8 KB
    __shared__ int kcur[NKEY];       // 8 KB
    __shared__ int psum[256];
    __shared__ int dh[DMAX];
    __shared__ int2 stage[CAP];      // 36 KB
    int b = blockIdx.x;
    int tid = threadIdx.x;
    int gb = bbase[b];
    int n = bbase[b + 1] - gb;
    for (int j = tid; j < NKEY; j += 256) kcnt[j] = 0;
    dh[tid] = 0;
    __syncthreads();
    for (int i = tid; i < n; i += 256) {
        int x = epk[gb + i].x;
        int key = (((x >> 17) & (BROWS - 1)) << 4) | ((x >> 13) & 15);
        atomicAdd(&kcnt[key], 1);
    }
    __syncthreads();
    // thread tid (< BROWS) owns row tid's 16 bins
    int deg = 0;
    if (tid < BROWS) {
        int lo = tid << 4;
        #pragma unroll
        for (int j = 0; j < 16; ++j) deg += kcnt[lo + j];
    }
    int r_glob = (b << BSHIFT) + tid;
    if (tid < BROWS && r_glob < N_NODES) atomicAdd(&dh[min(deg, DMAX - 1)], 1);
    psum[tid] = deg;
    __syncthreads();
    for (int off = 1; off < 256; off <<= 1) {
        int p = (tid >= off) ? psum[tid - off] : 0;
        __syncthreads();
        psum[tid] += p;
        __syncthreads();
    }
    int run = (tid > 0) ? psum[tid - 1] : 0;
    if (tid < BROWS && r_glob < N_NODES) starts[r_glob] = gb + run;
    if (b == 0 && tid == 0) starts[N_NODES] = N_EDGES;
    if (tid < BROWS) {
        int lo = tid << 4;
        #pragma unroll
        for (int j = 0; j < 16; ++j) {
            kcur[lo + j] = run;
            run += kcnt[lo + j];
        }
    }
    __syncthreads();
    {   // flush degree histogram
        int c = dh[tid];
        if (c) atomicAdd(&dcnt[tid], c);
    }
    for (int i = tid; i < n; i += 256) {
        int2 p = epk[gb + i];
        int key = (((p.x >> 17) & (BROWS - 1)) << 4) | ((p.x >> 13) & 15);
        int slot = atomicAdd(&kcur[key], 1);
        int2 fin;
        fin.x = p.x & 0x1FFFF;       // strip row_local
        fin.y = p.y;
        if (slot < CAP) stage[slot] = fin;
        else epk[gb + slot] = fin;   // overflow guard (statistically unreachable)
    }
    __syncthreads();
    for (int i = tid; i < n && i < CAP; i += 256) epk[gb + i] = stage[i];
}

// ---------------- degree scan + LDS-aggregated counting-sort scatter ----------------
__global__ __launch_bounds__(256) void dscan_kernel(const int* __restrict__ dcnt,
                                                    int* __restrict__ dcur) {
    __shared__ int part[DMAX];
    int tid = threadIdx.x;
    int v = dcnt[tid];
    part[tid] = v;
    __syncthreads();
    for (int off = 1; off < DMAX; off <<= 1) {
        int p = (tid >= off) ? part[tid - off] : 0;
        __syncthreads();
        part[tid] += p;
        __syncthreads();
    }
    dcur[tid] = part[tid] - v;   // exclusive
}

__global__ __launch_bounds__(256) void dscatter_kernel(const int* __restrict__ starts,
                                                       int* __restrict__ dcur,
                                                       int* __restrict__ perm) {
    __shared__ int h[DMAX];
    __shared__ int chunk[DMAX];
    int tid = threadIdx.x;
    int r = blockIdx.x * 256 + tid;
    h[tid] = 0;
    __syncthreads();
    int d = -1, rk = 0;
    if (r < N_NODES) {
        d = min(starts[r + 1] - starts[r], DMAX - 1);
        rk = atomicAdd(&h[d], 1);
    }
    __syncthreads();
    int c = h[tid];
    chunk[tid] = c ? atomicAdd(&dcur[tid], c) : 0;   // one atomic per (block,deg)
    __syncthreads();
    if (r < N_NODES) perm[chunk[d] + rk] = r;
}

// ---------------- SpMM: native 96B rows, 8 lanes/row x 12B, 4-edge unroll ----------------
// src/dst are [N][24] float (96B rows): layer 1 reads x directly, layer 6
// writes out directly. Each 96B gather touches exactly 2 64B sectors (same as
// padded 128B) but adjacent rows share sectors -> per-XCD compulsory 9.6MB.
#define ACC3(v, x0, x1, x2)                                  \
    a0 = fmaf(v, x0, a0); a1 = fmaf(v, x1, a1); a2 = fmaf(v, x2, a2);

__global__ __launch_bounds__(256) void spmm96_kernel(const int* __restrict__ starts,
                                                     const int* __restrict__ perm,
                                                     const int2* __restrict__ epk,
                                                     const float* __restrict__ src,
                                                     float* __restrict__ dst) {
    int t = blockIdx.x * blockDim.x + threadIdx.x;
    int g = t >> 3;
    if (g >= N_NODES) return;
    int rowi = perm[g];
    int sub = t & 7;
    int s = starts[rowi];
    int e = starts[rowi + 1];
    const int off = sub * 3;
    const float* sp = src + off;
    float a0 = 0.f, a1 = 0.f, a2 = 0.f;
    int i = s;
    for (; i + 3 < e; i += 4) {
        int2 p0 = epk[i];
        int2 p1 = epk[i + 1];
        int2 p2 = epk[i + 2];
        int2 p3 = epk[i + 3];
        const float* b0 = sp + p0.x * N_FEAT;
        const float* b1 = sp + p1.x * N_FEAT;
        const float* b2 = sp + p2.x * N_FEAT;
        const float* b3 = sp + p3.x * N_FEAT;
        float x00 = b0[0], x01 = b0[1], x02 = b0[2];
        float x10 = b1[0], x11 = b1[1], x12 = b1[2];
        float x20 = b2[0], x21 = b2[1], x22 = b2[2];
        float x30 = b3[0], x31 = b3[1], x32 = b3[2];
        float v0 = __int_as_float(p0.y);
        float v1 = __int_as_float(p1.y);
        float v2 = __int_as_float(p2.y);
        float v3 = __int_as_float(p3.y);
        ACC3(v0, x00, x01, x02);
        ACC3(v1, x10, x11, x12);
        ACC3(v2, x20, x21, x22);
        ACC3(v3, x30, x31, x32);
    }
    for (; i < e; ++i) {
        int2 p = epk[i];
        const float* b = sp + p.x * N_FEAT;
        float x0 = b[0], x1 = b[1], x2 = b[2];
        float v = __int_as_float(p.y);
        ACC3(v, x0, x1, x2);
    }
    float* dp = dst + rowi * N_FEAT + off;
    dp[0] = a0;
    dp[1] = a1;
    dp[2] = a2;
}

// ---------------- launch ----------------

extern "C" void kernel_launch(void* const* d_in, const int* in_sizes, int n_in,
                              void* d_out, int out_size, void* d_ws, size_t ws_size,
                              hipStream_t stream) {
    const float* x       = (const float*)d_in[0];
    const float* values  = (const float*)d_in[1];
    const int*   row_idx = (const int*)d_in[2];
    const int*   col_idx = (const int*)d_in[3];
    float* out = (float*)d_out;

    char* ws = (char*)d_ws;
    // workspace layout (~45.6MB, 128B-aligned offsets)
    int*   bcnt    = (int*)(ws + 0);          // NBUCK ints
    int*   bbase   = (int*)(ws + 4096);       // NBUCK+1 ints
    int*   bcursor = (int*)(ws + 8192);       // NBUCK ints
    int*   dcnt    = (int*)(ws + 12288);      // DMAX ints
    int*   dcur    = (int*)(ws + 16384);      // DMAX ints
    int*   starts  = (int*)(ws + 20480);      // N_NODES+1 ints
    int*   perm    = (int*)(ws + 420608);     // N_NODES ints
    int2*  epk     = (int2*)(ws + 820736);    // E * 8B = 25.6 MB
    float* bufA    = (float*)(ws + 26420864); // N*24 floats = 9.6 MB
    float* bufB    = (float*)(ws + 36020992); // N*24 floats = 9.6 MB

    zero_kernel<<<4, 256, 0, stream>>>(bcnt, NBUCK);
    zero_kernel<<<1, 256, 0, stream>>>(dcnt, DMAX);
    bhist_kernel<<<512, 256, 0, stream>>>(row_idx, bcnt);
    bscan_kernel<<<1, 1024, 0, stream>>>(bcnt, bbase, bcursor);
    part_kernel<<<NTILES, 256, 0, stream>>>(row_idx, col_idx, values, bcursor, epk);
    place_kernel<<<NBUCK, 256, 0, stream>>>(bbase, epk, starts, dcnt);

    const int node_blocks = (N_NODES + 255) / 256;
    dscan_kernel<<<1, DMAX, 0, stream>>>(dcnt, dcur);
    dscatter_kernel<<<node_blocks, 256, 0, stream>>>(starts, dcur, perm);

    const int spmm_blocks = (N_NODES * 8 + 255) / 256;
    spmm96_kernel<<<spmm_blocks, 256, 0, stream>>>(starts, perm, epk, x,    bufA);
    spmm96_kernel<<<spmm_blocks, 256, 0, stream>>>(starts, perm, epk, bufA, bufB);
    spmm96_kernel<<<spmm_blocks, 256, 0, stream>>>(starts, perm, epk, bufB, bufA);
    spmm96_kernel<<<spmm_blocks, 256, 0, stream>>>(starts, perm, epk, bufA, bufB);
    spmm96_kernel<<<spmm_blocks, 256, 0, stream>>>(starts, perm, epk, bufB, bufA);
    spmm96_kernel<<<spmm_blocks, 256, 0, stream>>>(starts, perm, epk, bufA, out);
}

// Round 11
// 454.329 us; speedup vs baseline: 1.1525x; 1.1525x over previous
//
#include <hip/hip_runtime.h>

#define N_NODES 100000
#define N_EDGES 3200000
#define N_FEAT 24
#define PADF4 8                         // padded row = 32 floats = 128B (one fetch line)
#define BSHIFT 7                        // 128 rows per bucket
#define BROWS 128
#define NBUCK ((N_NODES + BROWS - 1) >> BSHIFT)   // 782
#define EPT 16                          // edges per thread in partition
#define TILE (256 * EPT)                // 4096 edges per block-tile
#define NTILES ((N_EDGES + TILE - 1) / TILE)      // 782
#define CAP 4608                        // place stage entries (36KB) ~ mean+8sd
#define DMAX 256                        // degree buckets for balance sort
#define NKEY (BROWS * 16)               // 2048: (row_local 7b) x (colbin 4b)

// ---------------- small utils ----------------

__global__ void zero_kernel(int* __restrict__ p, int n) {
    int i = blockIdx.x * blockDim.x + threadIdx.x;
    if (i < n) p[i] = 0;
}

// ---------------- bucket histogram (LDS-aggregated) ----------------
__global__ __launch_bounds__(256) void bhist_kernel(const int* __restrict__ row,
                                                    int* __restrict__ bcnt) {
    __shared__ int h[NBUCK];
    for (int i = threadIdx.x; i < NBUCK; i += 256) h[i] = 0;
    __syncthreads();
    int stride = gridDim.x * blockDim.x;
    for (int i = blockIdx.x * blockDim.x + threadIdx.x; i < N_EDGES; i += stride)
        atomicAdd(&h[row[i] >> BSHIFT], 1);
    __syncthreads();
    for (int i = threadIdx.x; i < NBUCK; i += 256) {
        int c = h[i];
        if (c) atomicAdd(&bcnt[i], c);
    }
}

// ---------------- bucket exclusive scan -> bbase[0..NBUCK], bcursor ----------------
__global__ __launch_bounds__(1024) void bscan_kernel(const int* __restrict__ bcnt,
                                                     int* __restrict__ bbase,
                                                     int* __restrict__ bcursor) {
    __shared__ int part[1024];
    int tid = threadIdx.x;
    int v = (tid < NBUCK) ? bcnt[tid] : 0;
    part[tid] = v;
    __syncthreads();
    for (int off = 1; off < 1024; off <<= 1) {
        int p = (tid >= off) ? part[tid - off] : 0;
        __syncthreads();
        part[tid] += p;
        __syncthreads();
    }
    int ex = (tid > 0) ? part[tid - 1] : 0;
    if (tid <= NBUCK) {
        bbase[tid] = ex;              // bbase[NBUCK] == N_EDGES
        if (tid < NBUCK) bcursor[tid] = ex;
    }
}

// ---------------- level 1: partition edges into bucket regions ----------------
__global__ __launch_bounds__(256) void part_kernel(const int* __restrict__ row,
                                                   const int* __restrict__ col,
                                                   const float* __restrict__ val,
                                                   int* __restrict__ bcursor,
                                                   int2* __restrict__ epk) {
    __shared__ int h[NBUCK];
    __shared__ int lstart[NBUCK];
    __shared__ int delta[NBUCK];      // gpos[b] - lstart[b]
    __shared__ int psum[256];
    __shared__ int2 stage[TILE];
    __shared__ unsigned short bidx[TILE];
    const int tid = threadIdx.x;
    for (int i = tid; i < NBUCK; i += 256) h[i] = 0;
    __syncthreads();

    const int tbase = blockIdx.x * TILE;
    const int m = min(TILE, N_EDGES - tbase);
    const int base = tbase + tid * EPT;
    int rowj[EPT], rk[EPT];
    #pragma unroll
    for (int j = 0; j < EPT; ++j) {
        int e = base + j;
        if (e < N_EDGES) {
            int r = row[e];
            rowj[j] = r;
            rk[j] = atomicAdd(&h[r >> BSHIFT], 1);
        } else rowj[j] = -1;
    }
    __syncthreads();

    {   // exclusive scan h -> lstart (chunk=4 per thread, 256*4 >= NBUCK)
        int lo = tid * 4;
        int hi = min(NBUCK, lo + 4);
        int s = 0;
        for (int j = lo; j < hi; ++j) s += h[j];
        psum[tid] = s;
        __syncthreads();
        for (int off = 1; off < 256; off <<= 1) {
            int p = (tid >= off) ? psum[tid - off] : 0;
            __syncthreads();
            psum[tid] += p;
            __syncthreads();
        }
        int run = (tid > 0) ? psum[tid - 1] : 0;
        for (int j = lo; j < hi; ++j) {
            lstart[j] = run;
            run += h[j];
        }
    }
    __syncthreads();

    // reserve global chunks (one atomic per (block,bucket))
    for (int i = tid; i < NBUCK; i += 256) {
        int c = h[i];
        int g = c ? atomicAdd(&bcursor[i], c) : 0;
        delta[i] = g - lstart[i];
    }
    __syncthreads();

    #pragma unroll
    for (int j = 0; j < EPT; ++j) {
        if (rowj[j] >= 0) {
            int e = base + j;
            int b = rowj[j] >> BSHIFT;
            int rl = rowj[j] & (BROWS - 1);
            int slot = lstart[b] + rk[j];
            int2 pk;
            pk.x = col[e] | (rl << 17);   // col < 2^17, rl < 2^7
            pk.y = __float_as_int(val[e]);
            stage[slot] = pk;
            bidx[slot] = (unsigned short)b;
        }
    }
    __syncthreads();

    for (int i = tid; i < m; i += 256) {
        int b = bidx[i];
        epk[delta[b] + i] = stage[i];
    }
}

// ---------------- level 2: CSR placement, column-sorted within each row ----------------
// key = (row_local << 4) | (col >> 13). Emits starts[] + degree histogram.
__global__ __launch_bounds__(256) void place_kernel(const int* __restrict__ bbase,
                                                    int2* __restrict__ epk,
                                                    int* __restrict__ starts,
                                                    int* __restrict__ dcnt) {
    __shared__ int kcnt[NKEY];       // 8 KB
    __shared__ int kcur[NKEY];       // 8 KB
    __shared__ int psum[256];
    __shared__ int dh[DMAX];
    __shared__ int2 stage[CAP];      // 36 KB
    int b = blockIdx.x;
    int tid = threadIdx.x;
    int gb = bbase[b];
    int n = bbase[b + 1] - gb;
    for (int j = tid; j < NKEY; j += 256) kcnt[j] = 0;
    dh[tid] = 0;
    __syncthreads();
    for (int i = tid; i < n; i += 256) {
        int x = epk[gb + i].x;
        int key = (((x >> 17) & (BROWS - 1)) << 4) | ((x >> 13) & 15);
        atomicAdd(&kcnt[key], 1);
    }
    __syncthreads();
    // thread tid (< BROWS) owns row tid's 16 bins
    int deg = 0;
    if (tid < BROWS) {
        int lo = tid << 4;
        #pragma unroll
        for (int j = 0; j < 16; ++j) deg += kcnt[lo + j];
    }
    int r_glob = (b << BSHIFT) + tid;
    if (tid < BROWS && r_glob < N_NODES) atomicAdd(&dh[min(deg, DMAX - 1)], 1);
    psum[tid] = deg;
    __syncthreads();
    for (int off = 1; off < 256; off <<= 1) {
        int p = (tid >= off) ? psum[tid - off] : 0;
        __syncthreads();
        psum[tid] += p;
        __syncthreads();
    }
    int run = (tid > 0) ? psum[tid - 1] : 0;
    if (tid < BROWS && r_glob < N_NODES) starts[r_glob] = gb + run;
    if (b == 0 && tid == 0) starts[N_NODES] = N_EDGES;
    if (tid < BROWS) {
        int lo = tid << 4;
        #pragma unroll
        for (int j = 0; j < 16; ++j) {
            kcur[lo + j] = run;
            run += kcnt[lo + j];
        }
    }
    __syncthreads();
    {   // flush degree histogram
        int c = dh[tid];
        if (c) atomicAdd(&dcnt[tid], c);
    }
    for (int i = tid; i < n; i += 256) {
        int2 p = epk[gb + i];
        int key = (((p.x >> 17) & (BROWS - 1)) << 4) | ((p.x >> 13) & 15);
        int slot = atomicAdd(&kcur[key], 1);
        int2 fin;
        fin.x = p.x & 0x1FFFF;       // strip row_local
        fin.y = p.y;
        if (slot < CAP) stage[slot] = fin;
        else epk[gb + slot] = fin;   // overflow guard (statistically unreachable)
    }
    __syncthreads();
    for (int i = tid; i < n && i < CAP; i += 256) epk[gb + i] = stage[i];
}

// ---------------- degree scan + LDS-aggregated counting-sort scatter ----------------
__global__ __launch_bounds__(256) void dscan_kernel(const int* __restrict__ dcnt,
                                                    int* __restrict__ dcur) {
    __shared__ int part[DMAX];
    int tid = threadIdx.x;
    int v = dcnt[tid];
    part[tid] = v;
    __syncthreads();
    for (int off = 1; off < DMAX; off <<= 1) {
        int p = (tid >= off) ? part[tid - off] : 0;
        __syncthreads();
        part[tid] += p;
        __syncthreads();
    }
    dcur[tid] = part[tid] - v;   // exclusive
}

__global__ __launch_bounds__(256) void dscatter_kernel(const int* __restrict__ starts,
                                                       int* __restrict__ dcur,
                                                       int* __restrict__ perm) {
    __shared__ int h[DMAX];
    __shared__ int chunk[DMAX];
    int tid = threadIdx.x;
    int r = blockIdx.x * 256 + tid;
    h[tid] = 0;
    __syncthreads();
    int d = -1, rk = 0;
    if (r < N_NODES) {
        d = min(starts[r + 1] - starts[r], DMAX - 1);
        rk = atomicAdd(&h[d], 1);
    }
    __syncthreads();
    int c = h[tid];
    chunk[tid] = c ? atomicAdd(&dcur[tid], c) : 0;   // one atomic per (block,deg)
    __syncthreads();
    if (r < N_NODES) perm[chunk[d] + rk] = r;
}

// ---------------- pad-copy: x [N][24] -> bufA [N][32] ----------------
__global__ __launch_bounds__(256) void pad_copy_kernel(const float4* __restrict__ x4,
                                                       float4* __restrict__ dst) {
    int t = blockIdx.x * blockDim.x + threadIdx.x;
    int r = t >> 3;
    if (r >= N_NODES) return;
    int sub = t & 7;
    float4 v;
    if (sub < 6) v = x4[r * 6 + sub];
    else         v = make_float4(0.f, 0.f, 0.f, 0.f);
    dst[r * PADF4 + sub] = v;
}

// ---------------- SpMM: 8 lanes/row, 1 float4/lane, 4-edge unroll ----------------
// Padded 128B rows: every gather is exactly one aligned fetch line.
#define ACC4(v, xv, a)                                       \
    a.x = fmaf(v, xv.x, a.x); a.y = fmaf(v, xv.y, a.y);      \
    a.z = fmaf(v, xv.z, a.z); a.w = fmaf(v, xv.w, a.w);

__global__ __launch_bounds__(256) void spmm_pad_kernel(const int* __restrict__ starts,
                                                       const int* __restrict__ perm,
                                                       const int2* __restrict__ epk,
                                                       const float4* __restrict__ src,
                                                       float4* __restrict__ dst) {
    int t = blockIdx.x * blockDim.x + threadIdx.x;
    int g = t >> 3;
    if (g >= N_NODES) return;
    int rowi = perm[g];
    int sub = t & 7;
    int s = starts[rowi];
    int e = starts[rowi + 1];
    const float4* sp = src + sub;
    float4 acc = make_float4(0.f, 0.f, 0.f, 0.f);
    int i = s;
    for (; i + 3 < e; i += 4) {
        int2 p0 = epk[i];
        int2 p1 = epk[i + 1];
        int2 p2 = epk[i + 2];
        int2 p3 = epk[i + 3];
        float4 x0 = sp[p0.x * PADF4];
        float4 x1 = sp[p1.x * PADF4];
        float4 x2 = sp[p2.x * PADF4];
        float4 x3 = sp[p3.x * PADF4];
        float v0 = __int_as_float(p0.y);
        float v1 = __int_as_float(p1.y);
        float v2 = __int_as_float(p2.y);
        float v3 = __int_as_float(p3.y);
        ACC4(v0, x0, acc);
        ACC4(v1, x1, acc);
        ACC4(v2, x2, acc);
        ACC4(v3, x3, acc);
    }
    for (; i < e; ++i) {
        int2 p = epk[i];
        float4 xv = sp[p.x * PADF4];
        float v = __int_as_float(p.y);
        ACC4(v, xv, acc);
    }
    dst[rowi * PADF4 + sub] = acc;
}

__global__ __launch_bounds__(256) void spmm_final_kernel(const int* __restrict__ starts,
                                                         const int* __restrict__ perm,
                                                         const int2* __restrict__ epk,
                                                         const float4* __restrict__ src,
                                                         float* __restrict__ out) {
    int t = blockIdx.x * blockDim.x + threadIdx.x;
    int g = t >> 3;
    if (g >= N_NODES) return;
    int rowi = perm[g];
    int sub = t & 7;
    int s = starts[rowi];
    int e = starts[rowi + 1];
    const float4* sp = src + sub;
    float4 acc = make_float4(0.f, 0.f, 0.f, 0.f);
    int i = s;
    for (; i + 3 < e; i += 4) {
        int2 p0 = epk[i];
        int2 p1 = epk[i + 1];
        int2 p2 = epk[i + 2];
        int2 p3 = epk[i + 3];
        float4 x0 = sp[p0.x * PADF4];
        float4 x1 = sp[p1.x * PADF4];
        float4 x2 = sp[p2.x * PADF4];
        float4 x3 = sp[p3.x * PADF4];
        float v0 = __int_as_float(p0.y);
        float v1 = __int_as_float(p1.y);
        float v2 = __int_as_float(p2.y);
        float v3 = __int_as_float(p3.y);
        ACC4(v0, x0, acc);
        ACC4(v1, x1, acc);
        ACC4(v2, x2, acc);
        ACC4(v3, x3, acc);
    }
    for (; i < e; ++i) {
        int2 p = epk[i];
        float4 xv = sp[p.x * PADF4];
        float v = __int_as_float(p.y);
        ACC4(v, xv, acc);
    }
    if (sub < 6) *(float4*)(out + rowi * N_FEAT + sub * 4) = acc;
}

// ---------------- launch ----------------

extern "C" void kernel_launch(void* const* d_in, const int* in_sizes, int n_in,
                              void* d_out, int out_size, void* d_ws, size_t ws_size,
                              hipStream_t stream) {
    const float* x       = (const float*)d_in[0];
    const float* values  = (const float*)d_in[1];
    const int*   row_idx = (const int*)d_in[2];
    const int*   col_idx = (const int*)d_in[3];
    float* out = (float*)d_out;

    char* ws = (char*)d_ws;
    // workspace layout (~52MB, 128B-aligned offsets)
    int*    bcnt    = (int*)(ws + 0);          // NBUCK ints
    int*    bbase   = (int*)(ws + 4096);       // NBUCK+1 ints
    int*    bcursor = (int*)(ws + 8192);       // NBUCK ints
    int*    dcnt    = (int*)(ws + 12288);      // DMAX ints
    int*    dcur    = (int*)(ws + 16384);      // DMAX ints
    int*    starts  = (int*)(ws + 20480);      // N_NODES+1 ints
    int*    perm    = (int*)(ws + 420608);     // N_NODES ints
    int2*   epk     = (int2*)(ws + 820736);    // E * 8B = 25.6 MB
    float4* bufA    = (float4*)(ws + 26420864);// N*32 floats = 12.8 MB
    float4* bufB    = (float4*)(ws + 39220864);// N*32 floats = 12.8 MB

    zero_kernel<<<4, 256, 0, stream>>>(bcnt, NBUCK);
    zero_kernel<<<1, 256, 0, stream>>>(dcnt, DMAX);
    bhist_kernel<<<512, 256, 0, stream>>>(row_idx, bcnt);
    bscan_kernel<<<1, 1024, 0, stream>>>(bcnt, bbase, bcursor);
    part_kernel<<<NTILES, 256, 0, stream>>>(row_idx, col_idx, values, bcursor, epk);
    place_kernel<<<NBUCK, 256, 0, stream>>>(bbase, epk, starts, dcnt);

    const int node_blocks = (N_NODES + 255) / 256;
    dscan_kernel<<<1, DMAX, 0, stream>>>(dcnt, dcur);
    dscatter_kernel<<<node_blocks, 256, 0, stream>>>(starts, dcur, perm);

    const int spmm_blocks = (N_NODES * 8 + 255) / 256;
    pad_copy_kernel<<<spmm_blocks, 256, 0, stream>>>((const float4*)x, bufA);
    spmm_pad_kernel<<<spmm_blocks, 256, 0, stream>>>(starts, perm, epk, bufA, bufB);
    spmm_pad_kernel<<<spmm_blocks, 256, 0, stream>>>(starts, perm, epk, bufB, bufA);
    spmm_pad_kernel<<<spmm_blocks, 256, 0, stream>>>(starts, perm, epk, bufA, bufB);
    spmm_pad_kernel<<<spmm_blocks, 256, 0, stream>>>(starts, perm, epk, bufB, bufA);
    spmm_pad_kernel<<<spmm_blocks, 256, 0, stream>>>(starts, perm, epk, bufA, bufB);
    spmm_final_kernel<<<spmm_blocks, 256, 0, stream>>>(starts, perm, epk, bufB, out);
}